// Round 5
// baseline (135.742 us; speedup 1.0000x reference)
//
#include <hip/hip_runtime.h>
#include <stdint.h>

// Problem constants: B=16, C=48, H=W=64, N_CORR=2048
#define BB 16
#define HW 4096
#define NC 2048
#define KB 96            // bytes per column of data (48 bf16)
#define GRPB 12288       // bytes per 128-col group: [6 chunks][128 cols][16B]
#define IMGB 393216      // bytes per (img,b) image: 32 groups

typedef __attribute__((ext_vector_type(8))) __bf16 bf16x8;
typedef __attribute__((ext_vector_type(8))) short short8;
typedef __attribute__((ext_vector_type(4))) float floatx4;

static __device__ __forceinline__ unsigned short f2bf(float f) {
    unsigned u = __builtin_bit_cast(unsigned, f);
    unsigned r = u + 0x7fffu + ((u >> 16) & 1u);    // RNE
    return (unsigned short)(r >> 16);
}

#define GLD16(g, l) __builtin_amdgcn_global_load_lds((const __attribute__((address_space(1))) void*)(g), (__attribute__((address_space(3))) void*)(l), 16, 0, 0)

// ---------------------------------------------------------------------------
// prep_fused (R16): dbp stored TILE-K-MAJOR: per (img,b), 32 groups of
// [chunk k 0..5][col c 0..127][16B].  Makes maxscore's DMA linear on BOTH
// sides (R15 post-mortem: strided global src = 6x L2-line amplification,
// -2.5 us), keeps KB=96 footprint, and LDS B-reads stay conflict-free.
//   blocks [0,512):   one (img,b,chunk): 256 cols x 48 fp32 coalesced reads,
//                     normalize, pack bf16 col-major in LDS, remap to
//                     tile-K-major on the coalesced write-out.
//   blocks [512,544): counting sort of each (dir,b) query segment by qi.
//   blocks [544,552): zero maxs2enc (atomicMax identity).
// ---------------------------------------------------------------------------
__global__ void prep_fused(const float* __restrict__ x1, const float* __restrict__ x2,
                           const int* __restrict__ ids, const int* __restrict__ fp2,
                           unsigned short* __restrict__ dbp,
                           int* __restrict__ perm, int* __restrict__ qcol_s,
                           int* __restrict__ aqpack, unsigned int* __restrict__ maxs2enc) {
    __shared__ __align__(16) unsigned char slab[24576 + 4096 + 1024];
    int bid = blockIdx.x, tid = threadIdx.x;
    if (bid < 512) {
        int img = bid >> 8;
        int b = (bid >> 4) & 15;
        int p0 = (bid & 15) * 256;
        int w = tid >> 6, l = tid & 63;
        const float* x = img ? x2 : x1;
        const float* base = x + ((size_t)b * 48 + w * 12) * HW + p0 + 4 * l;
        floatx4 v[12];
        floatx4 ps = {0.f, 0.f, 0.f, 0.f};
#pragma unroll
        for (int cc = 0; cc < 12; ++cc) {
            v[cc] = *(const floatx4*)(base + cc * HW);
#pragma unroll
            for (int q = 0; q < 4; ++q) ps[q] = fmaf(v[cc][q], v[cc][q], ps[q]);
        }
        float* psum = (float*)(slab + 24576);             // [4 waves][256 cols]
        float* rbuf = (float*)(slab + 24576 + 4096);      // [256 cols]
        *(floatx4*)(psum + w * 256 + 4 * l) = ps;
        __syncthreads();
        float s = psum[tid] + psum[256 + tid] + psum[512 + tid] + psum[768 + tid];
        rbuf[tid] = 1.f / fmaxf(sqrtf(s), 1e-12f);
        __syncthreads();
        floatx4 rv = *(const floatx4*)(rbuf + 4 * l);
#pragma unroll
        for (int q = 0; q < 4; ++q) {
            unsigned u[6];
#pragma unroll
            for (int p = 0; p < 6; ++p) {
                u[p] = (unsigned)f2bf(v[2 * p][q] * rv[q]) |
                       ((unsigned)f2bf(v[2 * p + 1][q] * rv[q]) << 16);
            }
            unsigned char* dst = slab + (4 * l + q) * KB + w * 24;  // 8-aligned
            *(uint2*)(dst + 0)  = make_uint2(u[0], u[1]);
            *(uint2*)(dst + 8)  = make_uint2(u[2], u[3]);
            *(uint2*)(dst + 16) = make_uint2(u[4], u[5]);
        }
        __syncthreads();
        // write-out: remap col-major slab -> tile-K-major global, coalesced
        unsigned char* dstb = (unsigned char*)dbp + (size_t)(img * BB + b) * IMGB
                              + (p0 >> 7) * GRPB;
#pragma unroll
        for (int i = 0; i < 6; ++i) {                     // 2 groups * 12288 B
            int L = i * 4096 + tid * 16;
            int g = L / GRPB;                             // 0..1
            int r = L - g * GRPB;
            int k = r >> 11;                              // chunk 0..5
            int c = (r & 2047) >> 4;                      // col 0..127
            *(floatx4*)(dstb + L) = *(const floatx4*)(slab + (g * 128 + c) * KB + k * 16);
        }
    } else if (bid < 544) {
        int* hist = (int*)slab;
        int* base = hist + 64;
        int seg = bid - 512;                      // dir*16 + b
        int dir = seg >> 4, b = seg & 15;
        if (tid < 64) hist[tid] = 0;
        __syncthreads();
#pragma unroll
        for (int k = 0; k < 8; ++k) {
            int n = k * 256 + tid;
            int idv = ids[b * NC + n];
            int i2 = fp2[b * 2 * NC + n];
            int qi = (dir == 0) ? i2 : (idv >> 6);
            atomicAdd(&hist[qi], 1);
        }
        __syncthreads();
        if (tid == 0) {
            int run = 0;
            for (int k = 0; k < 64; ++k) { base[k] = run; run += hist[k]; }
        }
        __syncthreads();
#pragma unroll
        for (int k = 0; k < 8; ++k) {
            int n = k * 256 + tid;
            int idv = ids[b * NC + n];
            int i2 = fp2[b * 2 * NC + n];
            int j2 = fp2[b * 2 * NC + NC + n];
            int qi, qj, qcol;
            if (dir == 0) { qi = i2; qj = j2; qcol = idv; }
            else          { qi = idv >> 6; qj = idv & 63; qcol = i2 * 64 + j2; }
            int slot = atomicAdd(&base[qi], 1);
            perm[seg * NC + slot] = n;
            qcol_s[seg * NC + slot] = qcol;
            aqpack[seg * NC + slot] = (qi << 8) | qj;
        }
    } else {
        int t = (bid - 544) * 256 + tid;          // [0, 2048)
        uint4* p = (uint4*)maxs2enc;              // 16384 uint4 total
        uint4 z = {0u, 0u, 0u, 0u};
#pragma unroll
        for (int k = 0; k < 8; ++k) p[k * 2048 + t] = z;
    }
}

// ---------------------------------------------------------------------------
// maxscore_mfma (R16): tile-K-major dbp -> DMA linear both sides (12 KB/tile,
// 16-line instrs), LDS B-reads contiguous per quarter-wave (0 conflicts).
// Grid 2048 via MTILE-split (16 mtiles x 128 queries/block; nq in [0,4)
// unchanged, 8 tiles/block): prologue/epilogue halve WITH compute (R14's
// nq-split halved compute only), total atomics unchanged, 8 blocks/CU queued
// vs 6 resident (LDS 24576) smooths the active-path work imbalance that held
// mean occupancy at ~26% (mean/max block dur ~0.5 at exactly-4-blocks/CU).
// launch_bounds(256,4) kept (R13: (256,6) -> VGPR 40 -> 383 MB spill).
// K=48: A-frag quads 2-3 of the 2nd MFMA zeroed; B garbage (chunk 4/5
// reread) contributes 0.
// ---------------------------------------------------------------------------
#define TILEB 12288      // [6][128][16B]

static __device__ __forceinline__ void dma_tile(const unsigned char* g, unsigned char* l,
                                                int wave, int lane) {
#pragma unroll
    for (int rr = 0; rr < 3; ++rr)
        GLD16(g + rr * 4096 + wave * 1024 + lane * 16, l + rr * 4096 + wave * 1024);
}

__global__ __launch_bounds__(256, 4) void maxscore_mfma(
    const unsigned short* __restrict__ dbp,
    const int* __restrict__ perm, const int* __restrict__ qcol_s,
    const int* __restrict__ aqpack, unsigned int* __restrict__ maxs2enc) {
    __shared__ __align__(16) unsigned char smem[2 * TILEB];  // 24576 B

    int tid = threadIdx.x, wave = tid >> 6, lane = tid & 63;
    int quad = lane >> 4, cl = lane & 15;
    int gid = blockIdx.x;
    int seg = gid & 31, dir = seg >> 4, b = seg & 15;
    int rest = gid >> 5, mtile = rest & 15, nq = rest >> 4;  // nq in [0,4)
    int qbase = mtile * 128;
    int dbimg = 1 - dir;

    // A-fragments: 16B gathers from tile-K-major dbp (query image = dir)
    const unsigned char* dbQ = (const unsigned char*)dbp + (size_t)(dir * BB + b) * IMGB;
    short8 z8 = {0, 0, 0, 0, 0, 0, 0, 0};
    short8 afr[2][2];
#pragma unroll
    for (int t = 0; t < 2; ++t) {
        int slot = qbase + wave * 32 + t * 16 + cl;       // A[m=lane&15]
        int qc = qcol_s[seg * NC + slot];
        const unsigned char* src = dbQ + (qc >> 7) * GRPB + (qc & 127) * 16;
        afr[t][0] = *(const short8*)(src + quad * 2048);
        // second K=32 MFMA: k' in [16,32) (quads 2,3) is beyond K=48 -> zero A
        afr[t][1] = z8;
        if (quad < 2) afr[t][1] = *(const short8*)(src + (4 + quad) * 2048);
    }
    // Anchors for this lane's C/D rows (row = quad*4+r)
    float qif[2][4], qjc[2][4];
    float cl_f = (float)cl;
#pragma unroll
    for (int t = 0; t < 2; ++t)
#pragma unroll
        for (int r = 0; r < 4; ++r) {
            int slot = qbase + wave * 32 + t * 16 + quad * 4 + r;
            int ap = aqpack[seg * NC + slot];
            qif[t][r] = (float)(ap >> 8);
            qjc[t][r] = (float)(ap & 255) - cl_f;         // qj - lane col offset
        }
    // Wave's sorted qi range (32 consecutive sorted slots)
    int wb = seg * NC + qbase + wave * 32;
    int qimin = __builtin_amdgcn_readfirstlane(aqpack[wb] >> 8);
    int qimax = __builtin_amdgcn_readfirstlane(aqpack[wb + 31] >> 8);

    const unsigned char* dsrc = (const unsigned char*)dbp
        + (size_t)(dbimg * BB + b) * IMGB + (size_t)nq * 8 * GRPB;
    dma_tile(dsrc, smem, wave, lane);                     // prefetch tile 0

    const floatx4 zf = {0.f, 0.f, 0.f, 0.f};
    float mx[2][4];
#pragma unroll
    for (int t = 0; t < 2; ++t)
#pragma unroll
        for (int r = 0; r < 4; ++r) mx[t][r] = -1e30f;

    // B-read LDS offsets (K-major): b0 chunk = quad, b1 chunk = 4+(quad&1)
    int b0_off = quad * 2048 + cl * 16;
    int b1_off = (4 + (quad & 1)) * 2048 + cl * 16;

    for (int tile = 0; tile < 8; ++tile) {
        unsigned char* buf = smem + (tile & 1) * TILEB;
        __syncthreads();
        if (tile + 1 < 8)
            dma_tile(dsrc + (tile + 1) * TILEB, smem + ((tile + 1) & 1) * TILEB, wave, lane);
        int mi0 = nq * 16 + tile * 2;                     // two db rows per tile
#pragma unroll
        for (int half = 0; half < 2; ++half) {
            int mi = mi0 + half;
            bool active = (mi >= qimin - 4) && (mi <= qimax + 4);   // wave-uniform
            if (active) {
                float mi_f = (float)mi;
                bool rowok[2][4];
#pragma unroll
                for (int t = 0; t < 2; ++t)
#pragma unroll
                    for (int r = 0; r < 4; ++r)
                        rowok[t][r] = fabsf(qif[t][r] - mi_f) > 4.0f;
#pragma unroll
                for (int js = 0; js < 4; ++js) {
                    int sub = half * 4 + js;
                    float jj = (float)(js * 16);
                    short8 b0 = *(const short8*)(buf + b0_off + sub * 256);
                    short8 b1 = *(const short8*)(buf + b1_off + sub * 256);
#pragma unroll
                    for (int t = 0; t < 2; ++t) {
                        floatx4 acc = __builtin_amdgcn_mfma_f32_16x16x32_bf16(
                            __builtin_bit_cast(bf16x8, afr[t][0]),
                            __builtin_bit_cast(bf16x8, b0), zf, 0, 0, 0);
                        acc = __builtin_amdgcn_mfma_f32_16x16x32_bf16(
                            __builtin_bit_cast(bf16x8, afr[t][1]),
                            __builtin_bit_cast(bf16x8, b1), acc, 0, 0, 0);
#pragma unroll
                        for (int r = 0; r < 4; ++r) {
                            float dj = qjc[t][r] - jj;
                            bool ok = rowok[t][r] || (fabsf(dj) > 4.0f);
                            mx[t][r] = ok ? fmaxf(mx[t][r], acc[r]) : mx[t][r];
                        }
                    }
                }
            } else {                                      // all rows allowed: 1 op/elem
#pragma unroll
                for (int js = 0; js < 4; ++js) {
                    int sub = half * 4 + js;
                    short8 b0 = *(const short8*)(buf + b0_off + sub * 256);
                    short8 b1 = *(const short8*)(buf + b1_off + sub * 256);
#pragma unroll
                    for (int t = 0; t < 2; ++t) {
                        floatx4 acc = __builtin_amdgcn_mfma_f32_16x16x32_bf16(
                            __builtin_bit_cast(bf16x8, afr[t][0]),
                            __builtin_bit_cast(bf16x8, b0), zf, 0, 0, 0);
                        acc = __builtin_amdgcn_mfma_f32_16x16x32_bf16(
                            __builtin_bit_cast(bf16x8, afr[t][1]),
                            __builtin_bit_cast(bf16x8, b1), acc, 0, 0, 0);
#pragma unroll
                        for (int r = 0; r < 4; ++r)
                            mx[t][r] = fmaxf(mx[t][r], acc[r]);
                    }
                }
            }
        }
    }

    // reduce max over the 16 lanes of each quad (disjoint col subsets)
#pragma unroll
    for (int t = 0; t < 2; ++t)
#pragma unroll
        for (int r = 0; r < 4; ++r) {
            float v = mx[t][r];
            v = fmaxf(v, __shfl_xor(v, 1, 16));
            v = fmaxf(v, __shfl_xor(v, 2, 16));
            v = fmaxf(v, __shfl_xor(v, 4, 16));
            v = fmaxf(v, __shfl_xor(v, 8, 16));
            mx[t][r] = v;
        }
    if (cl == 0) {
#pragma unroll
        for (int t = 0; t < 2; ++t)
#pragma unroll
            for (int r = 0; r < 4; ++r) {
                int slot = qbase + wave * 32 + t * 16 + quad * 4 + r;
                int orig = perm[seg * NC + slot];
                float v = mx[t][r] + 2.0f;                // > 0: uint-monotone
                atomicMax(&maxs2enc[(size_t)seg * NC + orig],
                          __builtin_bit_cast(unsigned, v));
            }
    }
}

// ---------------------------------------------------------------------------
// loss: pos-distance from tile-K-major dbp bf16 columns (consistent rounding
// with the neg path), decode/merge the two direction maxes, weighted
// partials. grid = 128.
// ---------------------------------------------------------------------------
__global__ void loss_kernel(const float* __restrict__ att1, const float* __restrict__ att2,
                            const int* __restrict__ ids, const int* __restrict__ fp2,
                            const unsigned short* __restrict__ dbp,
                            const unsigned int* __restrict__ maxs2enc,
                            float* __restrict__ pnum, float* __restrict__ pden) {
    int b = blockIdx.x >> 3, chunk = blockIdx.x & 7;
    int tid = threadIdx.x;
    int n = chunk * 256 + tid;
    int idv = ids[b * NC + n];
    int i2 = fp2[b * 2 * NC + n], j2 = fp2[b * 2 * NC + NC + n];
    int c2 = i2 * 64 + j2;
    const unsigned char* a4 = (const unsigned char*)dbp + (size_t)(0 * BB + b) * IMGB
                              + (idv >> 7) * GRPB + (idv & 127) * 16;
    const unsigned char* b4 = (const unsigned char*)dbp + (size_t)(1 * BB + b) * IMGB
                              + (c2 >> 7) * GRPB + (c2 & 127) * 16;
    float dot = 0.f;
#pragma unroll
    for (int i = 0; i < 6; ++i) {                         // 6 chunks x 16 B
        uint4 xa = *(const uint4*)(a4 + i * 2048);
        uint4 xb = *(const uint4*)(b4 + i * 2048);
        const unsigned* xu = (const unsigned*)&xa;
        const unsigned* yu = (const unsigned*)&xb;
#pragma unroll
        for (int w = 0; w < 4; ++w) {
            float xl = __builtin_bit_cast(float, xu[w] << 16);
            float xh = __builtin_bit_cast(float, xu[w] & 0xffff0000u);
            float yl = __builtin_bit_cast(float, yu[w] << 16);
            float yh = __builtin_bit_cast(float, yu[w] & 0xffff0000u);
            dot = fmaf(xl, yl, fmaf(xh, yh, dot));
        }
    }
    float m0 = __builtin_bit_cast(float, maxs2enc[(size_t)(0 * BB + b) * NC + n]) - 2.0f;
    float m1 = __builtin_bit_cast(float, maxs2enc[(size_t)(1 * BB + b) * NC + n]) - 2.0f;
    float ms = fmaxf(m0, m1);
    float diff = (2.f - 2.f * dot) - (2.f - 2.f * ms);
    float w = att1[b * HW + idv] * att2[b * HW + c2];
    float num = w * fmaxf(0.f, 1.f + diff);
    float den = w;
    __shared__ float sn[256], sd[256];
    sn[tid] = num; sd[tid] = den;
    __syncthreads();
    for (int s = 128; s > 0; s >>= 1) {
        if (tid < s) { sn[tid] += sn[tid + s]; sd[tid] += sd[tid + s]; }
        __syncthreads();
    }
    if (tid == 0) { pnum[blockIdx.x] = sn[0]; pden[blockIdx.x] = sd[0]; }
}

__global__ void final_kernel(const float* __restrict__ pnum, const float* __restrict__ pden,
                             float* __restrict__ out) {
    int tid = threadIdx.x;
    __shared__ float r[16];
    if (tid < 16) {
        float n = 0.f, d = 0.f;
#pragma unroll
        for (int c = 0; c < 8; ++c) { n += pnum[tid * 8 + c]; d += pden[tid * 8 + c]; }
        r[tid] = n / d;
    }
    __syncthreads();
    if (tid == 0) {
        float s = 0.f;
#pragma unroll
        for (int k = 0; k < 16; ++k) s += r[k];
        out[0] = s * (1.f / BB);
    }
}

extern "C" void kernel_launch(void* const* d_in, const int* in_sizes, int n_in,
                              void* d_out, int out_size, void* d_ws, size_t ws_size,
                              hipStream_t stream) {
    const float* x1  = (const float*)d_in[0];
    const float* x2  = (const float*)d_in[1];
    const float* att1 = (const float*)d_in[2];
    const float* att2 = (const float*)d_in[3];
    const int* ids   = (const int*)d_in[4];
    const int* fp2   = (const int*)d_in[5];
    float* out = (float*)d_out;

    // ws layout (bytes), ~13.6 MB. (R8 finding: the harness poisons the FULL
    // d_ws allocation every iteration (~44 us) regardless of use.)
    unsigned char* w = (unsigned char*)d_ws;
    unsigned short* dbp = (unsigned short*)(w + 0);          // 2*16*393216 = 12,582,912
    int* perm    = (int*)(w + 12582912);                     // 32*2048*4 = 262,144
    int* qcol_s  = (int*)(w + 12845056);                     // 262,144
    int* aqpack  = (int*)(w + 13107200);                     // 262,144
    unsigned int* maxs2enc = (unsigned int*)(w + 13369344);  // 262,144
    float* pnum  = (float*)(w + 13631488);                   // 512
    float* pden  = (float*)(w + 13632000);                   // 512

    prep_fused<<<dim3(552), dim3(256), 0, stream>>>(x1, x2, ids, fp2, dbp,
                                                    perm, qcol_s, aqpack, maxs2enc);
    maxscore_mfma<<<dim3(2048), dim3(256), 0, stream>>>(dbp, perm, qcol_s, aqpack, maxs2enc);
    loss_kernel<<<dim3(128), dim3(256), 0, stream>>>(att1, att2, ids, fp2, dbp, maxs2enc, pnum, pden);
    final_kernel<<<dim3(1), dim3(64), 0, stream>>>(pnum, pden, out);
}

// Round 6
// 129.256 us; speedup vs baseline: 1.0502x; 1.0502x over previous
//
#include <hip/hip_runtime.h>
#include <stdint.h>

// Problem constants: B=16, C=48, H=W=64, N_CORR=2048
#define BB 16
#define HW 4096
#define NC 2048
#define KB 96            // bytes per column of data (48 bf16)
#define GRPB 12288       // bytes per 128-col group: [6 chunks][128 cols][16B]
#define IMGB 393216      // bytes per (img,b) image: 32 groups

typedef __attribute__((ext_vector_type(8))) __bf16 bf16x8;
typedef __attribute__((ext_vector_type(8))) short short8;
typedef __attribute__((ext_vector_type(4))) float floatx4;

static __device__ __forceinline__ unsigned short f2bf(float f) {
    unsigned u = __builtin_bit_cast(unsigned, f);
    unsigned r = u + 0x7fffu + ((u >> 16) & 1u);    // RNE
    return (unsigned short)(r >> 16);
}

#define GLD16(g, l) __builtin_amdgcn_global_load_lds((const __attribute__((address_space(1))) void*)(g), (__attribute__((address_space(3))) void*)(l), 16, 0, 0)

// ---------------------------------------------------------------------------
// prep_fused (R16): dbp stored TILE-K-MAJOR: per (img,b), 32 groups of
// [chunk k 0..5][col c 0..127][16B].  DMA linear on both sides, KB=96
// footprint, conflict-free LDS B-reads.
//   blocks [0,512):   one (img,b,chunk): 256 cols x 48 fp32 coalesced reads,
//                     normalize, pack bf16 col-major in LDS, remap to
//                     tile-K-major on the coalesced write-out.
//   blocks [512,544): counting sort of each (dir,b) query segment by qi.
//   blocks [544,552): zero maxs2enc (atomicMax identity).
// ---------------------------------------------------------------------------
__global__ void prep_fused(const float* __restrict__ x1, const float* __restrict__ x2,
                           const int* __restrict__ ids, const int* __restrict__ fp2,
                           unsigned short* __restrict__ dbp,
                           int* __restrict__ perm, int* __restrict__ qcol_s,
                           int* __restrict__ aqpack, unsigned int* __restrict__ maxs2enc) {
    __shared__ __align__(16) unsigned char slab[24576 + 4096 + 1024];
    int bid = blockIdx.x, tid = threadIdx.x;
    if (bid < 512) {
        int img = bid >> 8;
        int b = (bid >> 4) & 15;
        int p0 = (bid & 15) * 256;
        int w = tid >> 6, l = tid & 63;
        const float* x = img ? x2 : x1;
        const float* base = x + ((size_t)b * 48 + w * 12) * HW + p0 + 4 * l;
        floatx4 v[12];
        floatx4 ps = {0.f, 0.f, 0.f, 0.f};
#pragma unroll
        for (int cc = 0; cc < 12; ++cc) {
            v[cc] = *(const floatx4*)(base + cc * HW);
#pragma unroll
            for (int q = 0; q < 4; ++q) ps[q] = fmaf(v[cc][q], v[cc][q], ps[q]);
        }
        float* psum = (float*)(slab + 24576);             // [4 waves][256 cols]
        float* rbuf = (float*)(slab + 24576 + 4096);      // [256 cols]
        *(floatx4*)(psum + w * 256 + 4 * l) = ps;
        __syncthreads();
        float s = psum[tid] + psum[256 + tid] + psum[512 + tid] + psum[768 + tid];
        rbuf[tid] = 1.f / fmaxf(sqrtf(s), 1e-12f);
        __syncthreads();
        floatx4 rv = *(const floatx4*)(rbuf + 4 * l);
#pragma unroll
        for (int q = 0; q < 4; ++q) {
            unsigned u[6];
#pragma unroll
            for (int p = 0; p < 6; ++p) {
                u[p] = (unsigned)f2bf(v[2 * p][q] * rv[q]) |
                       ((unsigned)f2bf(v[2 * p + 1][q] * rv[q]) << 16);
            }
            unsigned char* dst = slab + (4 * l + q) * KB + w * 24;  // 8-aligned
            *(uint2*)(dst + 0)  = make_uint2(u[0], u[1]);
            *(uint2*)(dst + 8)  = make_uint2(u[2], u[3]);
            *(uint2*)(dst + 16) = make_uint2(u[4], u[5]);
        }
        __syncthreads();
        // write-out: remap col-major slab -> tile-K-major global, coalesced
        unsigned char* dstb = (unsigned char*)dbp + (size_t)(img * BB + b) * IMGB
                              + (p0 >> 7) * GRPB;
#pragma unroll
        for (int i = 0; i < 6; ++i) {                     // 2 groups * 12288 B
            int L = i * 4096 + tid * 16;
            int g = L / GRPB;                             // 0..1
            int r = L - g * GRPB;
            int k = r >> 11;                              // chunk 0..5
            int c = (r & 2047) >> 4;                      // col 0..127
            *(floatx4*)(dstb + L) = *(const floatx4*)(slab + (g * 128 + c) * KB + k * 16);
        }
    } else if (bid < 544) {
        int* hist = (int*)slab;
        int* base = hist + 64;
        int seg = bid - 512;                      // dir*16 + b
        int dir = seg >> 4, b = seg & 15;
        if (tid < 64) hist[tid] = 0;
        __syncthreads();
#pragma unroll
        for (int k = 0; k < 8; ++k) {
            int n = k * 256 + tid;
            int idv = ids[b * NC + n];
            int i2 = fp2[b * 2 * NC + n];
            int qi = (dir == 0) ? i2 : (idv >> 6);
            atomicAdd(&hist[qi], 1);
        }
        __syncthreads();
        if (tid == 0) {
            int run = 0;
            for (int k = 0; k < 64; ++k) { base[k] = run; run += hist[k]; }
        }
        __syncthreads();
#pragma unroll
        for (int k = 0; k < 8; ++k) {
            int n = k * 256 + tid;
            int idv = ids[b * NC + n];
            int i2 = fp2[b * 2 * NC + n];
            int j2 = fp2[b * 2 * NC + NC + n];
            int qi, qj, qcol;
            if (dir == 0) { qi = i2; qj = j2; qcol = idv; }
            else          { qi = idv >> 6; qj = idv & 63; qcol = i2 * 64 + j2; }
            int slot = atomicAdd(&base[qi], 1);
            perm[seg * NC + slot] = n;
            qcol_s[seg * NC + slot] = qcol;
            aqpack[seg * NC + slot] = (qi << 8) | qj;
        }
    } else {
        int t = (bid - 544) * 256 + tid;          // [0, 2048)
        uint4* p = (uint4*)maxs2enc;              // 16384 uint4 total
        uint4 z = {0u, 0u, 0u, 0u};
#pragma unroll
        for (int k = 0; k < 8; ++k) p[k * 2048 + t] = z;
    }
}

// ---------------------------------------------------------------------------
// maxscore_mfma (R17): R16 + STRIDED nq decomposition.  R16 post-mortem:
// all 5 structural variants converge at ~46-49 us with no pipe >35% —
// the floor is work imbalance: a block's 16 CONSECUTIVE mi either overlap
// its waves' qi-window (all tiles masked path, ~1.6x cost) or none do;
// CUs stacked with active blocks are the critical path (occupancy 35%).
// Fix: tile t -> group g = t*4 + nq (mi {2g,2g+1}); every block sweeps the
// full mi range at stride 8 -> every block gets the SAME ~1-2 active tiles
// -> uniform block cost.  DMA per tile is still one contiguous GRPB chunk.
// launch_bounds(256,4) kept (R13: (256,6) -> VGPR 40 cap -> 383 MB spill).
// K=48: A-frag quads 2-3 of the 2nd MFMA zeroed; B garbage contributes 0.
// ---------------------------------------------------------------------------
#define TILEB 12288      // [6][128][16B] == GRPB

static __device__ __forceinline__ void dma_tile(const unsigned char* g, unsigned char* l,
                                                int wave, int lane) {
#pragma unroll
    for (int rr = 0; rr < 3; ++rr)
        GLD16(g + rr * 4096 + wave * 1024 + lane * 16, l + rr * 4096 + wave * 1024);
}

__global__ __launch_bounds__(256, 4) void maxscore_mfma(
    const unsigned short* __restrict__ dbp,
    const int* __restrict__ perm, const int* __restrict__ qcol_s,
    const int* __restrict__ aqpack, unsigned int* __restrict__ maxs2enc) {
    __shared__ __align__(16) unsigned char smem[2 * TILEB];  // 24576 B

    int tid = threadIdx.x, wave = tid >> 6, lane = tid & 63;
    int quad = lane >> 4, cl = lane & 15;
    int gid = blockIdx.x;
    int seg = gid & 31, dir = seg >> 4, b = seg & 15;
    int rest = gid >> 5, mtile = rest & 15, nq = rest >> 4;  // nq in [0,4)
    int qbase = mtile * 128;
    int dbimg = 1 - dir;

    // A-fragments: 16B gathers from tile-K-major dbp (query image = dir)
    const unsigned char* dbQ = (const unsigned char*)dbp + (size_t)(dir * BB + b) * IMGB;
    short8 z8 = {0, 0, 0, 0, 0, 0, 0, 0};
    short8 afr[2][2];
#pragma unroll
    for (int t = 0; t < 2; ++t) {
        int slot = qbase + wave * 32 + t * 16 + cl;       // A[m=lane&15]
        int qc = qcol_s[seg * NC + slot];
        const unsigned char* src = dbQ + (qc >> 7) * GRPB + (qc & 127) * 16;
        afr[t][0] = *(const short8*)(src + quad * 2048);
        // second K=32 MFMA: k' in [16,32) (quads 2,3) is beyond K=48 -> zero A
        afr[t][1] = z8;
        if (quad < 2) afr[t][1] = *(const short8*)(src + (4 + quad) * 2048);
    }
    // Anchors for this lane's C/D rows (row = quad*4+r)
    float qif[2][4], qjc[2][4];
    float cl_f = (float)cl;
#pragma unroll
    for (int t = 0; t < 2; ++t)
#pragma unroll
        for (int r = 0; r < 4; ++r) {
            int slot = qbase + wave * 32 + t * 16 + quad * 4 + r;
            int ap = aqpack[seg * NC + slot];
            qif[t][r] = (float)(ap >> 8);
            qjc[t][r] = (float)(ap & 255) - cl_f;         // qj - lane col offset
        }
    // Wave's sorted qi range (32 consecutive sorted slots)
    int wb = seg * NC + qbase + wave * 32;
    int qimin = __builtin_amdgcn_readfirstlane(aqpack[wb] >> 8);
    int qimax = __builtin_amdgcn_readfirstlane(aqpack[wb + 31] >> 8);

    const unsigned char* dbase = (const unsigned char*)dbp + (size_t)(dbimg * BB + b) * IMGB;
    dma_tile(dbase + (size_t)nq * GRPB, smem, wave, lane);   // prefetch g = 0*4+nq

    const floatx4 zf = {0.f, 0.f, 0.f, 0.f};
    float mx[2][4];
#pragma unroll
    for (int t = 0; t < 2; ++t)
#pragma unroll
        for (int r = 0; r < 4; ++r) mx[t][r] = -1e30f;

    // B-read LDS offsets (K-major): b0 chunk = quad, b1 chunk = 4+(quad&1)
    int b0_off = quad * 2048 + cl * 16;
    int b1_off = (4 + (quad & 1)) * 2048 + cl * 16;

    for (int tile = 0; tile < 8; ++tile) {
        unsigned char* buf = smem + (tile & 1) * TILEB;
        __syncthreads();
        if (tile + 1 < 8)
            dma_tile(dbase + (size_t)((tile + 1) * 4 + nq) * GRPB,
                     smem + ((tile + 1) & 1) * TILEB, wave, lane);
        int mi0 = (tile * 4 + nq) * 2;                    // two db rows per tile
#pragma unroll
        for (int half = 0; half < 2; ++half) {
            int mi = mi0 + half;
            bool active = (mi >= qimin - 4) && (mi <= qimax + 4);   // wave-uniform
            if (active) {
                float mi_f = (float)mi;
                bool rowok[2][4];
#pragma unroll
                for (int t = 0; t < 2; ++t)
#pragma unroll
                    for (int r = 0; r < 4; ++r)
                        rowok[t][r] = fabsf(qif[t][r] - mi_f) > 4.0f;
#pragma unroll
                for (int js = 0; js < 4; ++js) {
                    int sub = half * 4 + js;
                    float jj = (float)(js * 16);
                    short8 b0 = *(const short8*)(buf + b0_off + sub * 256);
                    short8 b1 = *(const short8*)(buf + b1_off + sub * 256);
#pragma unroll
                    for (int t = 0; t < 2; ++t) {
                        floatx4 acc = __builtin_amdgcn_mfma_f32_16x16x32_bf16(
                            __builtin_bit_cast(bf16x8, afr[t][0]),
                            __builtin_bit_cast(bf16x8, b0), zf, 0, 0, 0);
                        acc = __builtin_amdgcn_mfma_f32_16x16x32_bf16(
                            __builtin_bit_cast(bf16x8, afr[t][1]),
                            __builtin_bit_cast(bf16x8, b1), acc, 0, 0, 0);
#pragma unroll
                        for (int r = 0; r < 4; ++r) {
                            float dj = qjc[t][r] - jj;
                            bool ok = rowok[t][r] || (fabsf(dj) > 4.0f);
                            mx[t][r] = ok ? fmaxf(mx[t][r], acc[r]) : mx[t][r];
                        }
                    }
                }
            } else {                                      // all rows allowed: 1 op/elem
#pragma unroll
                for (int js = 0; js < 4; ++js) {
                    int sub = half * 4 + js;
                    short8 b0 = *(const short8*)(buf + b0_off + sub * 256);
                    short8 b1 = *(const short8*)(buf + b1_off + sub * 256);
#pragma unroll
                    for (int t = 0; t < 2; ++t) {
                        floatx4 acc = __builtin_amdgcn_mfma_f32_16x16x32_bf16(
                            __builtin_bit_cast(bf16x8, afr[t][0]),
                            __builtin_bit_cast(bf16x8, b0), zf, 0, 0, 0);
                        acc = __builtin_amdgcn_mfma_f32_16x16x32_bf16(
                            __builtin_bit_cast(bf16x8, afr[t][1]),
                            __builtin_bit_cast(bf16x8, b1), acc, 0, 0, 0);
#pragma unroll
                        for (int r = 0; r < 4; ++r)
                            mx[t][r] = fmaxf(mx[t][r], acc[r]);
                    }
                }
            }
        }
    }

    // reduce max over the 16 lanes of each quad (disjoint col subsets)
#pragma unroll
    for (int t = 0; t < 2; ++t)
#pragma unroll
        for (int r = 0; r < 4; ++r) {
            float v = mx[t][r];
            v = fmaxf(v, __shfl_xor(v, 1, 16));
            v = fmaxf(v, __shfl_xor(v, 2, 16));
            v = fmaxf(v, __shfl_xor(v, 4, 16));
            v = fmaxf(v, __shfl_xor(v, 8, 16));
            mx[t][r] = v;
        }
    if (cl == 0) {
#pragma unroll
        for (int t = 0; t < 2; ++t)
#pragma unroll
            for (int r = 0; r < 4; ++r) {
                int slot = qbase + wave * 32 + t * 16 + quad * 4 + r;
                int orig = perm[seg * NC + slot];
                float v = mx[t][r] + 2.0f;                // > 0: uint-monotone
                atomicMax(&maxs2enc[(size_t)seg * NC + orig],
                          __builtin_bit_cast(unsigned, v));
            }
    }
}

// ---------------------------------------------------------------------------
// loss: pos-distance from tile-K-major dbp bf16 columns (consistent rounding
// with the neg path), decode/merge the two direction maxes, weighted
// partials. grid = 128.
// ---------------------------------------------------------------------------
__global__ void loss_kernel(const float* __restrict__ att1, const float* __restrict__ att2,
                            const int* __restrict__ ids, const int* __restrict__ fp2,
                            const unsigned short* __restrict__ dbp,
                            const unsigned int* __restrict__ maxs2enc,
                            float* __restrict__ pnum, float* __restrict__ pden) {
    int b = blockIdx.x >> 3, chunk = blockIdx.x & 7;
    int tid = threadIdx.x;
    int n = chunk * 256 + tid;
    int idv = ids[b * NC + n];
    int i2 = fp2[b * 2 * NC + n], j2 = fp2[b * 2 * NC + NC + n];
    int c2 = i2 * 64 + j2;
    const unsigned char* a4 = (const unsigned char*)dbp + (size_t)(0 * BB + b) * IMGB
                              + (idv >> 7) * GRPB + (idv & 127) * 16;
    const unsigned char* b4 = (const unsigned char*)dbp + (size_t)(1 * BB + b) * IMGB
                              + (c2 >> 7) * GRPB + (c2 & 127) * 16;
    float dot = 0.f;
#pragma unroll
    for (int i = 0; i < 6; ++i) {                         // 6 chunks x 16 B
        uint4 xa = *(const uint4*)(a4 + i * 2048);
        uint4 xb = *(const uint4*)(b4 + i * 2048);
        const unsigned* xu = (const unsigned*)&xa;
        const unsigned* yu = (const unsigned*)&xb;
#pragma unroll
        for (int w = 0; w < 4; ++w) {
            float xl = __builtin_bit_cast(float, xu[w] << 16);
            float xh = __builtin_bit_cast(float, xu[w] & 0xffff0000u);
            float yl = __builtin_bit_cast(float, yu[w] << 16);
            float yh = __builtin_bit_cast(float, yu[w] & 0xffff0000u);
            dot = fmaf(xl, yl, fmaf(xh, yh, dot));
        }
    }
    float m0 = __builtin_bit_cast(float, maxs2enc[(size_t)(0 * BB + b) * NC + n]) - 2.0f;
    float m1 = __builtin_bit_cast(float, maxs2enc[(size_t)(1 * BB + b) * NC + n]) - 2.0f;
    float ms = fmaxf(m0, m1);
    float diff = (2.f - 2.f * dot) - (2.f - 2.f * ms);
    float w = att1[b * HW + idv] * att2[b * HW + c2];
    float num = w * fmaxf(0.f, 1.f + diff);
    float den = w;
    __shared__ float sn[256], sd[256];
    sn[tid] = num; sd[tid] = den;
    __syncthreads();
    for (int s = 128; s > 0; s >>= 1) {
        if (tid < s) { sn[tid] += sn[tid + s]; sd[tid] += sd[tid + s]; }
        __syncthreads();
    }
    if (tid == 0) { pnum[blockIdx.x] = sn[0]; pden[blockIdx.x] = sd[0]; }
}

__global__ void final_kernel(const float* __restrict__ pnum, const float* __restrict__ pden,
                             float* __restrict__ out) {
    int tid = threadIdx.x;
    __shared__ float r[16];
    if (tid < 16) {
        float n = 0.f, d = 0.f;
#pragma unroll
        for (int c = 0; c < 8; ++c) { n += pnum[tid * 8 + c]; d += pden[tid * 8 + c]; }
        r[tid] = n / d;
    }
    __syncthreads();
    if (tid == 0) {
        float s = 0.f;
#pragma unroll
        for (int k = 0; k < 16; ++k) s += r[k];
        out[0] = s * (1.f / BB);
    }
}

extern "C" void kernel_launch(void* const* d_in, const int* in_sizes, int n_in,
                              void* d_out, int out_size, void* d_ws, size_t ws_size,
                              hipStream_t stream) {
    const float* x1  = (const float*)d_in[0];
    const float* x2  = (const float*)d_in[1];
    const float* att1 = (const float*)d_in[2];
    const float* att2 = (const float*)d_in[3];
    const int* ids   = (const int*)d_in[4];
    const int* fp2   = (const int*)d_in[5];
    float* out = (float*)d_out;

    // ws layout (bytes), ~13.6 MB. (R8 finding: the harness poisons the FULL
    // d_ws allocation every iteration (~44 us) regardless of use.)
    unsigned char* w = (unsigned char*)d_ws;
    unsigned short* dbp = (unsigned short*)(w + 0);          // 2*16*393216 = 12,582,912
    int* perm    = (int*)(w + 12582912);                     // 32*2048*4 = 262,144
    int* qcol_s  = (int*)(w + 12845056);                     // 262,144
    int* aqpack  = (int*)(w + 13107200);                     // 262,144
    unsigned int* maxs2enc = (unsigned int*)(w + 13369344);  // 262,144
    float* pnum  = (float*)(w + 13631488);                   // 512
    float* pden  = (float*)(w + 13632000);                   // 512

    prep_fused<<<dim3(552), dim3(256), 0, stream>>>(x1, x2, ids, fp2, dbp,
                                                    perm, qcol_s, aqpack, maxs2enc);
    maxscore_mfma<<<dim3(2048), dim3(256), 0, stream>>>(dbp, perm, qcol_s, aqpack, maxs2enc);
    loss_kernel<<<dim3(128), dim3(256), 0, stream>>>(att1, att2, ids, fp2, dbp, maxs2enc, pnum, pden);
    final_kernel<<<dim3(1), dim3(64), 0, stream>>>(pnum, pden, out);
}